// Round 1
// baseline (791.454 us; speedup 1.0000x reference)
//
#include <hip/hip_runtime.h>
#include <hip/hip_bf16.h>
#include <stdint.h>

// MetaPN: 3-layer per-sample hypernetwork, restructured as 3 GEMMs with
// on-the-fly A = x ⊗ pe outer-product generation.
// D=256, DT=64, B=4096.  K_eff = 256*256 + 256 + 256 = 66048 (1032 tiles of 64).

typedef unsigned int u32;
typedef unsigned short u16;
typedef __attribute__((ext_vector_type(8))) short short8;
typedef __attribute__((ext_vector_type(4))) short short4v;
typedef __attribute__((ext_vector_type(4))) float f32x4;

#define DEV static __device__ __forceinline__

DEV float b2f(u16 u){ u32 i = ((u32)u)<<16; float f; __builtin_memcpy(&f,&i,4); return f; }
DEV u16 f2b(float f){ __hip_bfloat16 h = __float2bfloat16(f); u16 u; __builtin_memcpy(&u,&h,2); return u; }

DEV void gll16(const void* g, void* l){
  __builtin_amdgcn_global_load_lds((const __attribute__((address_space(1))) u32*)g,
                                   (__attribute__((address_space(3))) u32*)l, 16, 0, 0);
}

// ---------------- prep: pack weights into bf16 K-tiled swizzled layout -------
// Logical B element (k, n), k = kt*64 + g*8 + e  (g,e in 0..7) is stored at
// byte offset  kt*N*128 + n*128 + ((g ^ (n&7))<<4) + e*2.
// The XOR swizzle is baked into global layout so global_load_lds stays linear
// (guide §5 m104/m173) and ds_read_b128 fragment reads are conflict-free.

// tile[n][kk] = src[(rowbase+n)*sstride + colbase + kk], rowbase=(kt>>2)*rowblk,
// colbase=(kt&3)*64
__global__ void pack_rowsrc(const float* __restrict__ src, u16* __restrict__ dst,
                            int nShift, int sstride, int rowblk, int total){
  int gid = blockIdx.x*256 + threadIdx.x;
  if (gid >= total) return;
  int g  = gid & 7;
  int n  = (gid >> 3) & ((1<<nShift)-1);
  int kt = gid >> (3+nShift);
  int rowbase = (kt>>2)*rowblk;
  int colbase = (kt&3)*64;
  const float* s = src + (size_t)(rowbase + n)*sstride + colbase + g*8;
  f32x4 a = *(const f32x4*)s;
  f32x4 b = *(const f32x4*)(s+4);
  short8 p;
  p[0]=(short)f2b(a[0]); p[1]=(short)f2b(a[1]); p[2]=(short)f2b(a[2]); p[3]=(short)f2b(a[3]);
  p[4]=(short)f2b(b[0]); p[5]=(short)f2b(b[1]); p[6]=(short)f2b(b[2]); p[7]=(short)f2b(b[3]);
  size_t dbyte = (((size_t)kt<<nShift) + n)*128 + (size_t)((g ^ (n&7))<<4);
  *(short8*)((char*)dst + dbyte) = p;
}

// tile[n][kk] = src[(kt*64+kk)*N + n]   (column-major source: b2w/b3w)
__global__ void pack_colsrc(const float* __restrict__ src, u16* __restrict__ dst,
                            int nShift, int total){
  int gid = blockIdx.x*256 + threadIdx.x;
  if (gid >= total) return;
  int g  = gid & 7;
  int n  = (gid >> 3) & ((1<<nShift)-1);
  int kt = gid >> (3+nShift);
  int N  = 1<<nShift;
  const float* s = src + (size_t)(kt*64 + g*8)*N + n;
  short8 p;
  #pragma unroll
  for (int e=0;e<8;e++) p[e] = (short)f2b(s[(size_t)e*N]);
  size_t dbyte = (((size_t)kt<<nShift) + n)*128 + (size_t)((g ^ (n&7))<<4);
  *(short8*)((char*)dst + dbyte) = p;
}

__global__ void cvt_bf16(const float* __restrict__ src, u16* __restrict__ dst, int n4){
  int i = blockIdx.x*256 + threadIdx.x;
  if (i >= n4) return;
  f32x4 v = *(const f32x4*)(src + (size_t)i*4);
  short4v p;
  p[0]=(short)f2b(v[0]); p[1]=(short)f2b(v[1]); p[2]=(short)f2b(v[2]); p[3]=(short)f2b(v[3]);
  *(short4v*)(dst + (size_t)i*4) = p;
}

// ---------------- main GEMM -------------------------------------------------
// AMODE 0: A chunks = [c0*pe | c1*pe | pe]           (layer 1, KTOT=12 tiles)
// AMODE 1: A chunks = [x⊗pe (1024 tiles) | x (4) | pe (4)]   (layers 2,3)
template<int BM, int BN, int NT, int AMODE, int NSPLIT, int KTOT>
__launch_bounds__(NT)
__global__ void gemm_meta(const u16* __restrict__ Bt, const u16* __restrict__ peb,
                          const u16* __restrict__ xb, const float* __restrict__ coods,
                          float* __restrict__ part, int M, int N){
  constexpr int WN   = BN/32;
  constexpr int NWAVE= NT/64;
  constexpr int WM   = NWAVE/WN;
  constexpr int WMS  = BM/WM;
  constexpr int MF   = WMS/16;
  constexpr int NF   = 2;
  constexpr int CH   = (BN*8)/NT;   // 16B chunks per thread (B stage)
  constexpr int PA   = (BM*8)/NT;   // passes (A stage)
  constexpr int KPT  = KTOT/NSPLIT;

  __shared__ __align__(16) u16 As[BM*64];
  __shared__ __align__(16) u16 Bs[BN*64];

  const int t = threadIdx.x;
  const int w = t>>6, l = t&63;
  const int r0 = blockIdx.x*BM, n0 = blockIdx.y*BN;
  const int kt0 = blockIdx.z*KPT;
  const int wm = w/WN, wn = w%WN;
  const int lr = l&15, lk = l>>4;
  const int sg = t&7, srl = t>>3;

  f32x4 acc[MF][NF] = {};

  for (int kk = 0; kk < KPT; ++kk) {
    const int kt = kt0 + kk;
    // B stage: linear async copy (swizzle pre-baked in global layout)
    {
      const char* gb = (const char*)Bt + (size_t)kt*N*128 + (size_t)n0*128;
      #pragma unroll
      for (int p=0;p<CH;p++){
        int cb = p*NT + w*64;                    // wave-uniform chunk base
        gll16(gb + (size_t)(cb + l)*16, (char*)Bs + (size_t)cb*16);
      }
    }
    // A stage: compute rows of A into LDS (swizzled ds_write_b128)
    #pragma unroll
    for (int p=0;p<PA;p++){
      int r = p*(NT/8) + srl;
      int row = r0 + r;
      short8 out;
      if (AMODE == 0) {
        int sel = kt>>2; int i0 = (kt&3)*64;
        float sc = 1.f;
        if (sel==0)      sc = coods[row*2+0];
        else if (sel==1) sc = coods[row*2+1];
        const short8 pe8 = *(const short8*)(peb + (size_t)row*256 + i0 + sg*8);
        #pragma unroll
        for (int j=0;j<8;j++) out[j] = (short)f2b(sc * b2f((u16)pe8[j]));
      } else {
        if (kt < 1024) {
          int d = kt>>2; int i0 = (kt&3)*64;
          float xv = b2f(xb[(size_t)row*256 + d]);
          const short8 pe8 = *(const short8*)(peb + (size_t)row*256 + i0 + sg*8);
          #pragma unroll
          for (int j=0;j<8;j++) out[j] = (short)f2b(xv * b2f((u16)pe8[j]));
        } else if (kt < 1028) {
          int c0 = (kt-1024)*64;
          out = *(const short8*)(xb + (size_t)row*256 + c0 + sg*8);
        } else {
          int c0 = (kt-1028)*64;
          out = *(const short8*)(peb + (size_t)row*256 + c0 + sg*8);
        }
      }
      *(short8*)((char*)As + (size_t)r*128 + ((sg ^ (r&7))<<4)) = out;
    }
    __syncthreads();
    // MFMA
    #pragma unroll
    for (int ki=0; ki<2; ++ki){
      short8 af[MF], bfr[NF];
      const int gq = ki*4 + lk;
      #pragma unroll
      for (int mf=0; mf<MF; ++mf){
        int row = wm*WMS + mf*16 + lr;
        af[mf] = *(const short8*)((const char*)As + (size_t)row*128 + ((gq ^ (row&7))<<4));
      }
      #pragma unroll
      for (int nf=0; nf<NF; ++nf){
        int n = wn*32 + nf*16 + lr;
        bfr[nf] = *(const short8*)((const char*)Bs + (size_t)n*128 + ((gq ^ (n&7))<<4));
      }
      #pragma unroll
      for (int mf=0; mf<MF; ++mf)
        #pragma unroll
        for (int nf=0; nf<NF; ++nf)
          acc[mf][nf] = __builtin_amdgcn_mfma_f32_16x16x32_bf16(af[mf], bfr[nf], acc[mf][nf], 0,0,0);
    }
    __syncthreads();
  }
  // partial store
  float* pp = part + (size_t)blockIdx.z*M*N;
  #pragma unroll
  for (int mf=0; mf<MF; ++mf){
    #pragma unroll
    for (int nf=0; nf<NF; ++nf){
      int col = n0 + wn*32 + nf*16 + lr;
      #pragma unroll
      for (int rg=0; rg<4; ++rg){
        int row = r0 + wm*WMS + mf*16 + lk*4 + rg;
        pp[(size_t)row*N + col] = acc[mf][nf][rg];
      }
    }
  }
}

// ---------------- reductions / epilogues ------------------------------------
__global__ void reduce_ep1(const float* __restrict__ part, const float* __restrict__ coods,
                           const float* __restrict__ b1w, const float* __restrict__ b1b,
                           const float* __restrict__ alpha, u16* __restrict__ x1b, int total){
  int i = blockIdx.x*256 + threadIdx.x;
  if (i >= total) return;
  int b = i>>8, d = i&255;
  float s = part[i] + coods[b*2]*b1w[d] + coods[b*2+1]*b1w[256+d] + b1b[d];
  float a = alpha[0];
  s = s >= 0.f ? s : a*s;
  x1b[i] = f2b(s);
}

__global__ void reduce_ep2(const float* __restrict__ part, const float* __restrict__ b2b,
                           const float* __restrict__ alpha, u16* __restrict__ x2b, int total){
  int i = blockIdx.x*256 + threadIdx.x;
  if (i >= total) return;
  float s = part[i] + part[(size_t)total + i] + part[2*(size_t)total + i] + part[3*(size_t)total + i]
          + b2b[i&255];
  float a = alpha[0];
  s = s >= 0.f ? s : a*s;
  x2b[i] = f2b(s);
}

__global__ void reduce_ep3(const float* __restrict__ part, const float* __restrict__ b3b,
                           float* __restrict__ out, int total){
  int i = blockIdx.x*256 + threadIdx.x;
  if (i >= total) return;
  float s = b3b[i&63];
  #pragma unroll
  for (int j=0;j<8;j++) s += part[(size_t)j*total + i];
  out[i] = s;
}

// ---------------- host ------------------------------------------------------
extern "C" void kernel_launch(void* const* d_in, const int* in_sizes, int n_in,
                              void* d_out, int out_size, void* d_ws, size_t ws_size,
                              hipStream_t stream){
  const float* coods = (const float*)d_in[0];
  const float* pe    = (const float*)d_in[1];
  const float* W1w   = (const float*)d_in[2];
  const float* b1w   = (const float*)d_in[3];
  const float* W1b   = (const float*)d_in[4];
  const float* b1b   = (const float*)d_in[5];
  const float* W2w   = (const float*)d_in[6];
  const float* b2w   = (const float*)d_in[7];
  const float* W2b   = (const float*)d_in[8];
  const float* b2b   = (const float*)d_in[9];
  const float* W3w   = (const float*)d_in[10];
  const float* b3w   = (const float*)d_in[11];
  const float* W3b   = (const float*)d_in[12];
  const float* b3b   = (const float*)d_in[13];
  const float* alpha = (const float*)d_in[14];
  float* out = (float*)d_out;

  char* ws = (char*)d_ws;
  size_t off = 0;
  auto alloc = [&](size_t bytes)->void*{ void* p = ws + off; off += (bytes + 255) & ~(size_t)255; return p; };
  u16*   B2   = (u16*)  alloc(1032ull*256*128);   // 32.25 MB
  u16*   B3   = (u16*)  alloc(1032ull*64*128);    //  8.06 MB
  u16*   B1   = (u16*)  alloc(12ull*256*128);     //  0.38 MB
  u16*   peb  = (u16*)  alloc(4096ull*256*2);
  u16*   x1b  = (u16*)  alloc(4096ull*256*2);
  u16*   x2b  = (u16*)  alloc(4096ull*256*2);
  float* part = (float*)alloc(4ull*4096*256*4);   // 16 MB shared partials
  if (ws_size < off) return;  // workspace too small: fail visibly (no launches)

  const int M = 4096;

  // --- pack weights ---
  // layer 2 B: [perm(W2w) | b2w_mat | W2b^T]
  pack_rowsrc<<<2097152/256, 256, 0, stream>>>(W2w, B2, 8, 256, 256, 2097152);
  pack_colsrc<<<8192/256,    256, 0, stream>>>(b2w, B2 + 1024ull*16384, 8, 8192);
  pack_rowsrc<<<8192/256,    256, 0, stream>>>(W2b, B2 + 1028ull*16384, 8, 256, 0, 8192);
  // layer 3 B: [perm(W3w) | b3w_mat | W3b^T]
  pack_rowsrc<<<524288/256,  256, 0, stream>>>(W3w, B3, 6, 256, 64, 524288);
  pack_colsrc<<<2048/256,    256, 0, stream>>>(b3w, B3 + 1024ull*4096, 6, 2048);
  pack_rowsrc<<<2048/256,    256, 0, stream>>>(W3b, B3 + 1028ull*4096, 6, 256, 0, 2048);
  // layer 1 B: [W1wA^T | W1wB^T | W1b^T]
  pack_rowsrc<<<16384/256,   256, 0, stream>>>(W1w, B1, 8, 256, 256, 16384);
  pack_rowsrc<<<8192/256,    256, 0, stream>>>(W1b, B1 + 8ull*16384, 8, 256, 0, 8192);
  // pe -> bf16
  cvt_bf16<<<262144/256, 256, 0, stream>>>(pe, peb, 262144);

  // --- layer 1 ---
  gemm_meta<64,64,256,0,1,12><<<dim3(64,4,1), 256, 0, stream>>>(B1, peb, nullptr, coods, part, M, 256);
  reduce_ep1<<<1048576/256, 256, 0, stream>>>(part, coods, b1w, b1b, alpha, x1b, 1048576);

  // --- layer 2 ---
  gemm_meta<256,64,512,1,4,1032><<<dim3(16,4,4), 512, 0, stream>>>(B2, peb, x1b, nullptr, part, M, 256);
  reduce_ep2<<<1048576/256, 256, 0, stream>>>(part, b2b, alpha, x2b, 1048576);

  // --- layer 3 ---
  gemm_meta<128,64,256,1,8,1032><<<dim3(32,1,8), 256, 0, stream>>>(B3, peb, x2b, nullptr, part, M, 64);
  reduce_ep3<<<262144/256, 256, 0, stream>>>(part, b3b, out, 262144);
}

// Round 2
// 550.393 us; speedup vs baseline: 1.4380x; 1.4380x over previous
//
#include <hip/hip_runtime.h>
#include <hip/hip_bf16.h>
#include <stdint.h>

// MetaPN: 3-layer per-sample hypernetwork, restructured as 3 GEMMs with
// on-the-fly A = x ⊗ pe outer-product generation.
// D=256, DT=64, B=4096.  K_eff = 256*256 + 256 + 256 = 66048 (1032 tiles of 64).

typedef unsigned int u32;
typedef unsigned short u16;
typedef __attribute__((ext_vector_type(8))) short short8;
typedef __attribute__((ext_vector_type(4))) short short4v;
typedef __attribute__((ext_vector_type(4))) float f32x4;

#define DEV static __device__ __forceinline__

DEV float b2f(u16 u){ u32 i = ((u32)u)<<16; float f; __builtin_memcpy(&f,&i,4); return f; }
DEV u16 f2b(float f){ __hip_bfloat16 h = __float2bfloat16(f); u16 u; __builtin_memcpy(&u,&h,2); return u; }

DEV void gll16(const void* g, void* l){
  __builtin_amdgcn_global_load_lds((const __attribute__((address_space(1))) u32*)g,
                                   (__attribute__((address_space(3))) u32*)l, 16, 0, 0);
}

// ---------------- prep: pack weights into bf16 K-tiled swizzled layout -------
// Logical B element (k, n), k = kt*64 + g*8 + e  (g,e in 0..7) is stored at
// byte offset  kt*N*128 + n*128 + ((g ^ (n&7))<<4) + e*2.
// Swizzle baked into global layout so global_load_lds stays linear (m104/m173)
// and ds_read_b128 fragment reads are conflict-free.

__global__ void pack_rowsrc(const float* __restrict__ src, u16* __restrict__ dst,
                            int nShift, int sstride, int rowblk, int total){
  int gid = blockIdx.x*256 + threadIdx.x;
  if (gid >= total) return;
  int g  = gid & 7;
  int n  = (gid >> 3) & ((1<<nShift)-1);
  int kt = gid >> (3+nShift);
  int rowbase = (kt>>2)*rowblk;
  int colbase = (kt&3)*64;
  const float* s = src + (size_t)(rowbase + n)*sstride + colbase + g*8;
  f32x4 a = *(const f32x4*)s;
  f32x4 b = *(const f32x4*)(s+4);
  short8 p;
  p[0]=(short)f2b(a[0]); p[1]=(short)f2b(a[1]); p[2]=(short)f2b(a[2]); p[3]=(short)f2b(a[3]);
  p[4]=(short)f2b(b[0]); p[5]=(short)f2b(b[1]); p[6]=(short)f2b(b[2]); p[7]=(short)f2b(b[3]);
  size_t dbyte = (((size_t)kt<<nShift) + n)*128 + (size_t)((g ^ (n&7))<<4);
  *(short8*)((char*)dst + dbyte) = p;
}

__global__ void pack_colsrc(const float* __restrict__ src, u16* __restrict__ dst,
                            int nShift, int total){
  int gid = blockIdx.x*256 + threadIdx.x;
  if (gid >= total) return;
  int g  = gid & 7;
  int n  = (gid >> 3) & ((1<<nShift)-1);
  int kt = gid >> (3+nShift);
  int N  = 1<<nShift;
  const float* s = src + (size_t)(kt*64 + g*8)*N + n;
  short8 p;
  #pragma unroll
  for (int e=0;e<8;e++) p[e] = (short)f2b(s[(size_t)e*N]);
  size_t dbyte = (((size_t)kt<<nShift) + n)*128 + (size_t)((g ^ (n&7))<<4);
  *(short8*)((char*)dst + dbyte) = p;
}

__global__ void cvt_bf16(const float* __restrict__ src, u16* __restrict__ dst, int n4){
  int i = blockIdx.x*256 + threadIdx.x;
  if (i >= n4) return;
  f32x4 v = *(const f32x4*)(src + (size_t)i*4);
  short4v p;
  p[0]=(short)f2b(v[0]); p[1]=(short)f2b(v[1]); p[2]=(short)f2b(v[2]); p[3]=(short)f2b(v[3]);
  *(short4v*)(dst + (size_t)i*4) = p;
}

// ---------------- main GEMM -------------------------------------------------
// AMODE 0: A chunks = [c0*pe | c1*pe | pe]           (layer 1, KTOT=12 tiles)
// AMODE 1: A chunks = [x⊗pe (1024 tiles) | x (4) | pe (4)]   (layers 2,3)
template<int BM, int BN, int NT, int AMODE, int NSPLIT, int KTOT>
__launch_bounds__(NT)
__global__ void gemm_meta(const u16* __restrict__ Bt, const u16* __restrict__ peb,
                          const u16* __restrict__ xb, const float* __restrict__ coods,
                          float* __restrict__ part, int M, int N){
  constexpr int WN   = BN/32;
  constexpr int NWAVE= NT/64;
  constexpr int WM   = NWAVE/WN;
  constexpr int WMS  = BM/WM;
  constexpr int MF   = WMS/16;
  constexpr int NF   = 2;
  constexpr int CH   = (BN*8)/NT;   // 16B chunks per thread (B stage)
  constexpr int PA   = (BM*8)/NT;   // passes (A stage)
  constexpr int KPT  = KTOT/NSPLIT;

  __shared__ __align__(16) u16 As[BM*64];
  __shared__ __align__(16) u16 Bs[BN*64];

  const int t = threadIdx.x;
  const int w = t>>6, l = t&63;
  const int r0 = blockIdx.x*BM, n0 = blockIdx.y*BN;
  const int kt0 = blockIdx.z*KPT;
  const int wm = w/WN, wn = w%WN;
  const int lr = l&15, lk = l>>4;
  const int sg = t&7, srl = t>>3;

  f32x4 acc[MF][NF] = {};

  for (int kk = 0; kk < KPT; ++kk) {
    const int kt = kt0 + kk;
    // B stage: linear async copy (swizzle pre-baked in global layout)
    {
      const char* gb = (const char*)Bt + (size_t)kt*N*128 + (size_t)n0*128;
      #pragma unroll
      for (int p=0;p<CH;p++){
        int cb = p*NT + w*64;                    // wave-uniform chunk base
        gll16(gb + (size_t)(cb + l)*16, (char*)Bs + (size_t)cb*16);
      }
    }
    // A stage: compute rows of A into LDS (swizzled ds_write_b128)
    #pragma unroll
    for (int p=0;p<PA;p++){
      int r = p*(NT/8) + srl;
      int row = r0 + r;
      short8 out;
      if (AMODE == 0) {
        int sel = kt>>2; int i0 = (kt&3)*64;
        float sc = 1.f;
        if (sel==0)      sc = coods[row*2+0];
        else if (sel==1) sc = coods[row*2+1];
        const short8 pe8 = *(const short8*)(peb + (size_t)row*256 + i0 + sg*8);
        #pragma unroll
        for (int j=0;j<8;j++) out[j] = (short)f2b(sc * b2f((u16)pe8[j]));
      } else {
        if (kt < 1024) {
          int d = kt>>2; int i0 = (kt&3)*64;
          float xv = b2f(xb[(size_t)row*256 + d]);
          const short8 pe8 = *(const short8*)(peb + (size_t)row*256 + i0 + sg*8);
          #pragma unroll
          for (int j=0;j<8;j++) out[j] = (short)f2b(xv * b2f((u16)pe8[j]));
        } else if (kt < 1028) {
          int c0 = (kt-1024)*64;
          out = *(const short8*)(xb + (size_t)row*256 + c0 + sg*8);
        } else {
          int c0 = (kt-1028)*64;
          out = *(const short8*)(peb + (size_t)row*256 + c0 + sg*8);
        }
      }
      *(short8*)((char*)As + (size_t)r*128 + ((sg ^ (r&7))<<4)) = out;
    }
    __syncthreads();
    // MFMA
    #pragma unroll
    for (int ki=0; ki<2; ++ki){
      short8 af[MF], bfr[NF];
      const int gq = ki*4 + lk;
      #pragma unroll
      for (int mf=0; mf<MF; ++mf){
        int row = wm*WMS + mf*16 + lr;
        af[mf] = *(const short8*)((const char*)As + (size_t)row*128 + ((gq ^ (row&7))<<4));
      }
      #pragma unroll
      for (int nf=0; nf<NF; ++nf){
        int n = wn*32 + nf*16 + lr;
        bfr[nf] = *(const short8*)((const char*)Bs + (size_t)n*128 + ((gq ^ (n&7))<<4));
      }
      #pragma unroll
      for (int mf=0; mf<MF; ++mf)
        #pragma unroll
        for (int nf=0; nf<NF; ++nf)
          acc[mf][nf] = __builtin_amdgcn_mfma_f32_16x16x32_bf16(af[mf], bfr[nf], acc[mf][nf], 0,0,0);
    }
    __syncthreads();
  }
  // partial store
  float* pp = part + (size_t)blockIdx.z*M*N;
  #pragma unroll
  for (int mf=0; mf<MF; ++mf){
    #pragma unroll
    for (int nf=0; nf<NF; ++nf){
      int col = n0 + wn*32 + nf*16 + lr;
      #pragma unroll
      for (int rg=0; rg<4; ++rg){
        int row = r0 + wm*WMS + mf*16 + lk*4 + rg;
        pp[(size_t)row*N + col] = acc[mf][nf][rg];
      }
    }
  }
}

// ---------------- reductions / epilogues ------------------------------------
__global__ void reduce_ep1(const float* __restrict__ part, const float* __restrict__ coods,
                           const float* __restrict__ b1w, const float* __restrict__ b1b,
                           const float* __restrict__ alpha, u16* __restrict__ x1b, int total){
  int i = blockIdx.x*256 + threadIdx.x;
  if (i >= total) return;
  int b = i>>8, d = i&255;
  float s = part[i] + coods[b*2]*b1w[d] + coods[b*2+1]*b1w[256+d] + b1b[d];
  float a = alpha[0];
  s = s >= 0.f ? s : a*s;
  x1b[i] = f2b(s);
}

__global__ void reduce_ep2(const float* __restrict__ part, const float* __restrict__ b2b,
                           const float* __restrict__ alpha, u16* __restrict__ x2b, int total){
  int i = blockIdx.x*256 + threadIdx.x;
  if (i >= total) return;
  float s = part[i] + part[(size_t)total + i] + part[2*(size_t)total + i] + part[3*(size_t)total + i]
          + b2b[i&255];
  float a = alpha[0];
  s = s >= 0.f ? s : a*s;
  x2b[i] = f2b(s);
}

__global__ void reduce_ep3(const float* __restrict__ part, const float* __restrict__ b3b,
                           float* __restrict__ out, int total){
  int i = blockIdx.x*256 + threadIdx.x;
  if (i >= total) return;
  float s = b3b[i&63];
  #pragma unroll
  for (int j=0;j<12;j++) s += part[(size_t)j*total + i];
  out[i] = s;
}

// ---------------- host ------------------------------------------------------
extern "C" void kernel_launch(void* const* d_in, const int* in_sizes, int n_in,
                              void* d_out, int out_size, void* d_ws, size_t ws_size,
                              hipStream_t stream){
  const float* coods = (const float*)d_in[0];
  const float* pe    = (const float*)d_in[1];
  const float* W1w   = (const float*)d_in[2];
  const float* b1w   = (const float*)d_in[3];
  const float* W1b   = (const float*)d_in[4];
  const float* b1b   = (const float*)d_in[5];
  const float* W2w   = (const float*)d_in[6];
  const float* b2w   = (const float*)d_in[7];
  const float* W2b   = (const float*)d_in[8];
  const float* b2b   = (const float*)d_in[9];
  const float* W3w   = (const float*)d_in[10];
  const float* b3w   = (const float*)d_in[11];
  const float* W3b   = (const float*)d_in[12];
  const float* b3b   = (const float*)d_in[13];
  const float* alpha = (const float*)d_in[14];
  float* out = (float*)d_out;

  char* ws = (char*)d_ws;
  size_t off = 0;
  auto alloc = [&](size_t bytes)->void*{ void* p = ws + off; off += (bytes + 255) & ~(size_t)255; return p; };
  u16*   B2   = (u16*)  alloc(1032ull*256*128);   // 32.25 MB
  u16*   B3   = (u16*)  alloc(1032ull*64*128);    //  8.06 MB
  u16*   B1   = (u16*)  alloc(12ull*256*128);     //  0.38 MB
  u16*   peb  = (u16*)  alloc(4096ull*256*2);
  u16*   x1b  = (u16*)  alloc(4096ull*256*2);
  u16*   x2b  = (u16*)  alloc(4096ull*256*2);
  float* part = (float*)alloc(4ull*4096*256*4);   // 16 MB shared partials
  if (ws_size < off) return;  // workspace too small: fail visibly (no launches)

  const int M = 4096;

  // --- pack weights ---
  pack_rowsrc<<<2097152/256, 256, 0, stream>>>(W2w, B2, 8, 256, 256, 2097152);
  pack_colsrc<<<8192/256,    256, 0, stream>>>(b2w, B2 + 1024ull*16384, 8, 8192);
  pack_rowsrc<<<8192/256,    256, 0, stream>>>(W2b, B2 + 1028ull*16384, 8, 256, 0, 8192);
  pack_rowsrc<<<524288/256,  256, 0, stream>>>(W3w, B3, 6, 256, 64, 524288);
  pack_colsrc<<<2048/256,    256, 0, stream>>>(b3w, B3 + 1024ull*4096, 6, 2048);
  pack_rowsrc<<<2048/256,    256, 0, stream>>>(W3b, B3 + 1028ull*4096, 6, 256, 0, 2048);
  pack_rowsrc<<<16384/256,   256, 0, stream>>>(W1w, B1, 8, 256, 256, 16384);
  pack_rowsrc<<<8192/256,    256, 0, stream>>>(W1b, B1 + 8ull*16384, 8, 256, 0, 8192);
  cvt_bf16<<<262144/256, 256, 0, stream>>>(pe, peb, 262144);

  // --- layer 1 ---
  gemm_meta<64,64,256,0,1,12><<<dim3(64,4,1), 256, 0, stream>>>(B1, peb, nullptr, coods, part, M, 256);
  reduce_ep1<<<1048576/256, 256, 0, stream>>>(part, coods, b1w, b1b, alpha, x1b, 1048576);

  // --- layer 2: BM=128/NT=512 -> grid 512 blocks = 2 blocks/CU (was 1) ---
  gemm_meta<128,64,512,1,4,1032><<<dim3(32,4,4), 512, 0, stream>>>(B2, peb, x1b, nullptr, part, M, 256);
  reduce_ep2<<<1048576/256, 256, 0, stream>>>(part, b2b, alpha, x2b, 1048576);

  // --- layer 3: BM=64/NT=256/NSPLIT=12 -> grid 768 blocks = 3 blocks/CU ---
  gemm_meta<64,64,256,1,12,1032><<<dim3(64,1,12), 256, 0, stream>>>(B3, peb, x2b, nullptr, part, M, 64);
  reduce_ep3<<<262144/256, 256, 0, stream>>>(part, b3b, out, 262144);
}

// Round 3
// 456.947 us; speedup vs baseline: 1.7320x; 1.2045x over previous
//
#include <hip/hip_runtime.h>
#include <hip/hip_bf16.h>
#include <stdint.h>

// MetaPN: 3-layer per-sample hypernetwork as 3 GEMMs with on-the-fly
// A = x ⊗ pe outer-product generation.  D=256, DT=64, B=4096.
// K_eff = 256*256 + 256 + 256 = 66048 (1032 tiles of 64).
// Round 3: BN=N (no y-split), dbuf LDS + single barrier/K-step (T3 minimum
// 2-phase), async A-operand loads (T14 split), split-K via atomics.

typedef unsigned int u32;
typedef unsigned short u16;
typedef __attribute__((ext_vector_type(8))) short short8;
typedef __attribute__((ext_vector_type(4))) short short4v;
typedef __attribute__((ext_vector_type(4))) float f32x4;

#define DEV static __device__ __forceinline__

DEV float b2f(u16 u){ u32 i = ((u32)u)<<16; float f; __builtin_memcpy(&f,&i,4); return f; }
DEV u16 f2b(float f){ __hip_bfloat16 h = __float2bfloat16(f); u16 u; __builtin_memcpy(&u,&h,2); return u; }

DEV void gll16(const void* g, void* l){
  __builtin_amdgcn_global_load_lds((const __attribute__((address_space(1))) u32*)g,
                                   (__attribute__((address_space(3))) u32*)l, 16, 0, 0);
}

// ---------------- prep: pack weights into bf16 K-tiled swizzled layout -------
// Logical B element (k, n), k = kt*64 + g*8 + e  (g,e in 0..7) stored at byte
// kt*N*128 + n*128 + ((g ^ (n&7))<<4) + e*2.  Swizzle baked into global layout
// so global_load_lds stays linear (m104/m173); ds_read_b128 conflict-free.

__global__ void pack_rowsrc(const float* __restrict__ src, u16* __restrict__ dst,
                            int nShift, int sstride, int rowblk, int total){
  int gid = blockIdx.x*256 + threadIdx.x;
  if (gid >= total) return;
  int g  = gid & 7;
  int n  = (gid >> 3) & ((1<<nShift)-1);
  int kt = gid >> (3+nShift);
  int rowbase = (kt>>2)*rowblk;
  int colbase = (kt&3)*64;
  const float* s = src + (size_t)(rowbase + n)*sstride + colbase + g*8;
  f32x4 a = *(const f32x4*)s;
  f32x4 b = *(const f32x4*)(s+4);
  short8 p;
  p[0]=(short)f2b(a[0]); p[1]=(short)f2b(a[1]); p[2]=(short)f2b(a[2]); p[3]=(short)f2b(a[3]);
  p[4]=(short)f2b(b[0]); p[5]=(short)f2b(b[1]); p[6]=(short)f2b(b[2]); p[7]=(short)f2b(b[3]);
  size_t dbyte = (((size_t)kt<<nShift) + n)*128 + (size_t)((g ^ (n&7))<<4);
  *(short8*)((char*)dst + dbyte) = p;
}

__global__ void pack_colsrc(const float* __restrict__ src, u16* __restrict__ dst,
                            int nShift, int total){
  int gid = blockIdx.x*256 + threadIdx.x;
  if (gid >= total) return;
  int g  = gid & 7;
  int n  = (gid >> 3) & ((1<<nShift)-1);
  int kt = gid >> (3+nShift);
  int N  = 1<<nShift;
  const float* s = src + (size_t)(kt*64 + g*8)*N + n;
  short8 p;
  #pragma unroll
  for (int e=0;e<8;e++) p[e] = (short)f2b(s[(size_t)e*N]);
  size_t dbyte = (((size_t)kt<<nShift) + n)*128 + (size_t)((g ^ (n&7))<<4);
  *(short8*)((char*)dst + dbyte) = p;
}

__global__ void cvt_bf16(const float* __restrict__ src, u16* __restrict__ dst, int n4){
  int i = blockIdx.x*256 + threadIdx.x;
  if (i >= n4) return;
  f32x4 v = *(const f32x4*)(src + (size_t)i*4);
  short4v p;
  p[0]=(short)f2b(v[0]); p[1]=(short)f2b(v[1]); p[2]=(short)f2b(v[2]); p[3]=(short)f2b(v[3]);
  *(short4v*)(dst + (size_t)i*4) = p;
}

// ---------------- main GEMM -------------------------------------------------
// AMODE 0: A chunks = [c0*pe | c1*pe | pe]           (layer 1, KTOT=12 tiles)
// AMODE 1: A chunks = [x⊗pe (1024 tiles) | x (4) | pe (4)]   (layers 2,3)
// BN == N.  Split-K over blockIdx.x % NSPLIT; partials accumulated atomically.
template<int BM, int BN, int NT, int NF, int AMODE, int NSPLIT, int KTOT>
__launch_bounds__(NT)
__global__ void gemm_meta(const u16* __restrict__ Bt, const u16* __restrict__ peb,
                          const u16* __restrict__ xb, const float* __restrict__ coods,
                          float* __restrict__ part){
  constexpr int WNS  = NF*16;
  constexpr int WN   = BN/WNS;
  constexpr int NWAVE= NT/64;
  constexpr int WM   = NWAVE/WN;
  constexpr int WMS  = BM/WM;
  constexpr int MF   = WMS/16;
  constexpr int CH   = (BN*8)/NT;   // 16B gll chunks per thread (B stage)
  constexpr int PA   = (BM*8)/NT;   // passes (A stage)
  constexpr int KPT  = KTOT/NSPLIT;

  __shared__ __align__(16) u16 As[2][BM*64];
  __shared__ __align__(16) u16 Bs[2][BN*64];

  const int t = threadIdx.x;
  const int w = t>>6, l = t&63;
  const int bid = blockIdx.x;
  const int zz = bid % NSPLIT;          // z first => z == XCD (mod 8) for L2 locality
  const int xx = bid / NSPLIT;
  const int r0 = xx*BM;
  const int kt0 = zz*KPT;
  const int wm = w/WN, wn = w%WN;
  const int lr = l&15, lk = l>>4;
  const int sg = t&7, srl = t>>3;

  short8 a8[PA];          // staged A operand (pe or x chunk)
  u16    axv[PA];         // x scalar (AMODE 1, kt<1024)
  float  asc[PA];         // coods scalar (AMODE 0)

  auto stage_load = [&](int buf, int kt){
    // B tile: async global->LDS, linear (swizzle pre-baked in global layout)
    const char* gb = (const char*)Bt + (size_t)kt*(BN*128);
    #pragma unroll
    for (int p=0;p<CH;p++){
      int cb = p*NT + w*64;             // wave-uniform chunk base
      gll16(gb + (size_t)(cb + l)*16, (char*)Bs[buf] + (size_t)cb*16);
    }
    // A operands -> registers (latency hidden under current tile's MFMA)
    #pragma unroll
    for (int p=0;p<PA;p++){
      int row = r0 + p*(NT/8) + srl;
      if (AMODE == 0) {
        int sel = kt>>2, i0 = (kt&3)*64;
        asc[p] = sel==0 ? coods[row*2+0] : (sel==1 ? coods[row*2+1] : 1.f);
        a8[p] = *(const short8*)(peb + (size_t)row*256 + i0 + sg*8);
      } else {
        if (kt < 1024) {
          int d = kt>>2, i0 = (kt&3)*64;
          axv[p] = xb[(size_t)row*256 + d];
          a8[p]  = *(const short8*)(peb + (size_t)row*256 + i0 + sg*8);
        } else if (kt < 1028) {
          a8[p]  = *(const short8*)(xb + (size_t)row*256 + (kt-1024)*64 + sg*8);
        } else {
          a8[p]  = *(const short8*)(peb + (size_t)row*256 + (kt-1028)*64 + sg*8);
        }
      }
    }
  };
  auto stage_write = [&](int buf, int kt){
    #pragma unroll
    for (int p=0;p<PA;p++){
      int r = p*(NT/8) + srl;
      short8 out;
      bool raw = (AMODE==0) ? ((kt>>2)==2) : (kt>=1024);
      if (raw) {
        out = a8[p];
      } else {
        float sc = (AMODE==0) ? asc[p] : b2f(axv[p]);
        #pragma unroll
        for (int j=0;j<8;j++) out[j] = (short)f2b(sc * b2f((u16)a8[p][j]));
      }
      *(short8*)((char*)As[buf] + (size_t)r*128 + ((sg ^ (r&7))<<4)) = out;
    }
  };

  f32x4 acc[MF][NF] = {};

  stage_load(0, kt0);
  stage_write(0, kt0);
  __syncthreads();

  for (int kk = 0; kk < KPT; ++kk) {
    const bool pf = (kk+1 < KPT);
    if (pf) stage_load((kk+1)&1, kt0+kk+1);      // gll B(next) + A loads
    const char* Ab = (const char*)As[kk&1];
    const char* Bb = (const char*)Bs[kk&1];
    #pragma unroll
    for (int ki=0; ki<2; ++ki){
      short8 af[MF], bfr[NF];
      const int gq = ki*4 + lk;
      #pragma unroll
      for (int mf=0; mf<MF; ++mf){
        int row = wm*WMS + mf*16 + lr;
        af[mf] = *(const short8*)(Ab + (size_t)row*128 + ((gq ^ (row&7))<<4));
      }
      #pragma unroll
      for (int nf=0; nf<NF; ++nf){
        int n = wn*WNS + nf*16 + lr;
        bfr[nf] = *(const short8*)(Bb + (size_t)n*128 + ((gq ^ (n&7))<<4));
      }
      #pragma unroll
      for (int mf=0; mf<MF; ++mf)
        #pragma unroll
        for (int nf=0; nf<NF; ++nf)
          acc[mf][nf] = __builtin_amdgcn_mfma_f32_16x16x32_bf16(af[mf], bfr[nf], acc[mf][nf], 0,0,0);
    }
    if (pf) stage_write((kk+1)&1, kt0+kk+1);     // cvt + ds_write A(next)
    __syncthreads();
  }

  // split-K accumulate
  #pragma unroll
  for (int mf=0; mf<MF; ++mf){
    #pragma unroll
    for (int nf=0; nf<NF; ++nf){
      int col = wn*WNS + nf*16 + lr;
      #pragma unroll
      for (int rg=0; rg<4; ++rg){
        int row = r0 + wm*WMS + mf*16 + lk*4 + rg;
        atomicAdd(&part[(size_t)row*BN + col], acc[mf][nf][rg]);
      }
    }
  }
}

// ---------------- epilogues -------------------------------------------------
__global__ void reduce_ep1(const float* __restrict__ part, const float* __restrict__ coods,
                           const float* __restrict__ b1w, const float* __restrict__ b1b,
                           const float* __restrict__ alpha, u16* __restrict__ x1b, int total){
  int i = blockIdx.x*256 + threadIdx.x;
  if (i >= total) return;
  int b = i>>8, d = i&255;
  float s = part[i] + coods[b*2]*b1w[d] + coods[b*2+1]*b1w[256+d] + b1b[d];
  float a = alpha[0];
  s = s >= 0.f ? s : a*s;
  x1b[i] = f2b(s);
}

__global__ void reduce_ep2(const float* __restrict__ part, const float* __restrict__ b2b,
                           const float* __restrict__ alpha, u16* __restrict__ x2b, int total){
  int i = blockIdx.x*256 + threadIdx.x;
  if (i >= total) return;
  float s = part[i] + b2b[i&255];
  float a = alpha[0];
  s = s >= 0.f ? s : a*s;
  x2b[i] = f2b(s);
}

__global__ void reduce_ep3(const float* __restrict__ part, const float* __restrict__ b3b,
                           float* __restrict__ out, int total){
  int i = blockIdx.x*256 + threadIdx.x;
  if (i >= total) return;
  out[i] = part[i] + b3b[i&63];
}

// ---------------- host ------------------------------------------------------
extern "C" void kernel_launch(void* const* d_in, const int* in_sizes, int n_in,
                              void* d_out, int out_size, void* d_ws, size_t ws_size,
                              hipStream_t stream){
  const float* coods = (const float*)d_in[0];
  const float* pe    = (const float*)d_in[1];
  const float* W1w   = (const float*)d_in[2];
  const float* b1w   = (const float*)d_in[3];
  const float* W1b   = (const float*)d_in[4];
  const float* b1b   = (const float*)d_in[5];
  const float* W2w   = (const float*)d_in[6];
  const float* b2w   = (const float*)d_in[7];
  const float* W2b   = (const float*)d_in[8];
  const float* b2b   = (const float*)d_in[9];
  const float* W3w   = (const float*)d_in[10];
  const float* b3w   = (const float*)d_in[11];
  const float* W3b   = (const float*)d_in[12];
  const float* b3b   = (const float*)d_in[13];
  const float* alpha = (const float*)d_in[14];
  float* out = (float*)d_out;

  char* ws = (char*)d_ws;
  size_t off = 0;
  auto alloc = [&](size_t bytes)->void*{ void* p = ws + off; off += (bytes + 255) & ~(size_t)255; return p; };
  u16*   B2   = (u16*)  alloc(1032ull*256*128);   // 32.25 MB
  u16*   B3   = (u16*)  alloc(1032ull*64*128);    //  8.06 MB
  u16*   B1   = (u16*)  alloc(12ull*256*128);     //  0.38 MB
  u16*   peb  = (u16*)  alloc(4096ull*256*2);
  u16*   x1b  = (u16*)  alloc(4096ull*256*2);
  u16*   x2b  = (u16*)  alloc(4096ull*256*2);
  float* part = (float*)alloc(4096ull*256*4);     // 4 MB (atomic accumulator)
  if (ws_size < off) return;

  // --- pack weights ---
  pack_rowsrc<<<2097152/256, 256, 0, stream>>>(W2w, B2, 8, 256, 256, 2097152);
  pack_colsrc<<<8192/256,    256, 0, stream>>>(b2w, B2 + 1024ull*16384, 8, 8192);
  pack_rowsrc<<<8192/256,    256, 0, stream>>>(W2b, B2 + 1028ull*16384, 8, 256, 0, 8192);
  pack_rowsrc<<<524288/256,  256, 0, stream>>>(W3w, B3, 6, 256, 64, 524288);
  pack_colsrc<<<2048/256,    256, 0, stream>>>(b3w, B3 + 1024ull*4096, 6, 2048);
  pack_rowsrc<<<2048/256,    256, 0, stream>>>(W3b, B3 + 1028ull*4096, 6, 256, 0, 2048);
  pack_rowsrc<<<16384/256,   256, 0, stream>>>(W1w, B1, 8, 256, 256, 16384);
  pack_rowsrc<<<8192/256,    256, 0, stream>>>(W1b, B1 + 8ull*16384, 8, 256, 0, 8192);
  cvt_bf16<<<262144/256, 256, 0, stream>>>(pe, peb, 262144);

  // --- layer 1: grid 64x4=256 blocks ---
  hipMemsetAsync(part, 0, 4096ull*256*4, stream);
  gemm_meta<64,256,512,4,0,4,12><<<256, 512, 0, stream>>>(B1, peb, nullptr, coods, part);
  reduce_ep1<<<1048576/256, 256, 0, stream>>>(part, coods, b1w, b1b, alpha, x1b, 1048576);

  // --- layer 2: grid 64x8=512 blocks, 2 blocks/CU (80KB LDS) ---
  hipMemsetAsync(part, 0, 4096ull*256*4, stream);
  gemm_meta<64,256,512,4,1,8,1032><<<512, 512, 0, stream>>>(B2, peb, x1b, nullptr, part);
  reduce_ep2<<<1048576/256, 256, 0, stream>>>(part, b2b, alpha, x2b, 1048576);

  // --- layer 3: grid 64x12=768 blocks, 3 blocks/CU ---
  hipMemsetAsync(part, 0, 4096ull*64*4, stream);
  gemm_meta<64,64,256,2,1,12,1032><<<768, 256, 0, stream>>>(B3, peb, x2b, nullptr, part);
  reduce_ep3<<<262144/256, 256, 0, stream>>>(part, b3b, out, 262144);
}